// Round 15
// baseline (245.776 us; speedup 1.0000x reference)
//
#include <hip/hip_runtime.h>
#include <hip/hip_bf16.h>
#include <stdint.h>
#include <math.h>

#define B_ 8
#define C_ 512
#define N_ 2048
#define H_ 8
#define D_ 64
#define HID_ 512

typedef short bf16x8 __attribute__((ext_vector_type(8)));
typedef float f32x4 __attribute__((ext_vector_type(4)));
typedef short short4v __attribute__((ext_vector_type(4)));

__device__ __forceinline__ float bf2f(unsigned short v) {
  union { float f; unsigned u; } c; c.u = ((unsigned)v) << 16; return c.f;
}
__device__ __forceinline__ unsigned short f2bf(float f) {
  union { float f; unsigned u; } c; c.f = f;
  unsigned u = c.u + 0x7FFFu + ((c.u >> 16) & 1u);
  return (unsigned short)(u >> 16);
}

// SESSION RULES:
//  - (R3/R6/R8, all ~0.1 absmax): no raw inline asm adjacent to TRANS-op
//    (v_exp) dataflow — INLINEASM defeats TRANS wait-state insertion.
//    R8 (asm cvt_pk + plain __expf) proved asm ALONE fails; R9 proved the
//    compiler-visible path passes. exp2-fold retried via exp2f() intrinsic.
//  - (R14 compile fail): __exp2f collides with glibc math.h macros — use
//    plain exp2f() (device overload lowers to v_exp_f32, hazard-safe).
//  - (R11 compile fail): no arrays of LDS pointers; use explicit ternaries.
//  - (R12): attn 8w x 32r and 4w x 64r both ~82-84 us — LDS-read BW is NOT
//    the attn limit; issue-mix bound at ~88% combined issue.
//  - (R13): attn grid-swap (bid%8=bh%8) cut FETCH 139->27 MB (K/V L2-resident).

// async global->LDS, 16B per lane. LDS dest is wave-uniform base + lane*16;
// any swizzle must be applied on the GLOBAL source address.
__device__ __forceinline__ void async_copy16(const void* g, void* l) {
  __builtin_amdgcn_global_load_lds((const __attribute__((address_space(1))) void*)g,
                                   (__attribute__((address_space(3))) void*)l,
                                   16, 0, 0);
}

// ---------------------------------------------------------------------------
// Kernel 1: channel LayerNorm + transpose, SINGLE global read of x.
// Round-15: slab halved to 32 n-columns (64 KB LDS) -> 2 blocks/CU (was 1).
// All DMA drains and the per-block barriers now overlap across the two
// co-resident blocks. Weight f32->bf16 conversion still hidden under the DMA.
// ---------------------------------------------------------------------------
__global__ __launch_bounds__(256) void ln_transpose(
    const float* __restrict__ x,            // (B, C, N) f32
    const float* __restrict__ g,            // (C,) f32
    unsigned short* __restrict__ xnt,       // (B, N, C) bf16
    const float* __restrict__ Ws1, unsigned short* __restrict__ Wd1, int n1,
    const float* __restrict__ Ws2, unsigned short* __restrict__ Wd2, int n2) {
  __shared__ __align__(16) float slab[C_ * 32];            // [c][n], 64 KB
  __shared__ __align__(16) unsigned short tile2[64 * 33];  // [c-chunk][n] bf16
  __shared__ float red[256], red2[256];
  __shared__ float meanS[32], rstdS[32];

  const int b = blockIdx.y, n0 = blockIdx.x * 32;
  const int t = threadIdx.x;
  const float* xb = x + (size_t)b * C_ * N_ + n0;

  // phase 1: DMA the slab (8 lanes per c-row, 4 f32/lane, 32 rows/call)
#pragma unroll
  for (int call = 0; call < 16; ++call) {
    int c = call * 32 + (t >> 3);
    async_copy16(&xb[(size_t)c * N_ + (t & 7) * 4], &slab[call * 1024 + t * 4]);
  }

  // weight conversion (former wcvt2), overlapped with the slab DMA
  {
    const int bid = blockIdx.y * gridDim.x + blockIdx.x;  // 0..511
    for (int i = bid * 256 + t; i < n1 + n2; i += 512 * 256) {
      const float4 v = (i < n1) ? ((const float4*)Ws1)[i] : ((const float4*)Ws2)[i - n1];
      short4v pk;
      pk[0] = (short)f2bf(v.x); pk[1] = (short)f2bf(v.y);
      pk[2] = (short)f2bf(v.z); pk[3] = (short)f2bf(v.w);
      if (i < n1) ((short4v*)Wd1)[i] = pk; else ((short4v*)Wd2)[i - n1] = pk;
    }
  }

  asm volatile("s_waitcnt vmcnt(0)" ::: "memory");
  __syncthreads();

  // phase 2: stats — 8 c-partials per n (lanes vary n: 2-way, free)
  {
    const int n = t & 31, cb = (t >> 5) * 64;
    float s = 0.f, s2 = 0.f;
    for (int c = cb; c < cb + 64; ++c) {
      float v = slab[c * 32 + n];
      s += v; s2 += v * v;
    }
    red[t] = s; red2[t] = s2;
  }
  __syncthreads();
  if (t < 32) {
    float ts = 0.f, ts2 = 0.f;
#pragma unroll
    for (int k = 0; k < 8; ++k) { ts += red[t + 32 * k]; ts2 += red2[t + 32 * k]; }
    float mean = ts * (1.0f / C_);
    float var  = ts2 * (1.0f / C_) - mean * mean;
    meanS[t] = mean;
    rstdS[t] = rsqrtf(var + 1e-5f);
  }
  __syncthreads();

  unsigned short* xout = xnt + ((size_t)b * N_ + n0) * C_;
  for (int c0 = 0; c0 < C_; c0 += 64) {
    // normalize into padded tile (lanes vary n: conflict-free)
    for (int e = t; e < 64 * 32; e += 256) {
      int cl = e >> 5, nl = e & 31;
      float v = slab[(c0 + cl) * 32 + nl];
      tile2[cl * 33 + nl] = f2bf((v - meanS[nl]) * rstdS[nl] * g[c0 + cl]);
    }
    __syncthreads();
    // transposed write: 4 c per lane, consecutive lanes -> consecutive c
    for (int e = t; e < 32 * 16; e += 256) {
      int nl = e >> 4, c4 = (e & 15) * 4;
      short4v pk;
#pragma unroll
      for (int j = 0; j < 4; ++j) pk[j] = (short)tile2[(c4 + j) * 33 + nl];
      *(short4v*)&xout[(size_t)nl * C_ + c0 + c4] = pk;
    }
    __syncthreads();
  }
}

// ---------------------------------------------------------------------------
// Kernel 2: QKV GEMM. 256x128 tile (8 waves, 512 thr), BK=64, single-buffered
// R9-proven staging/read pattern. Grid (16, 6, 8) = 768 blocks; LDS 48 KB.
// Epilogue: q -> (b,h,n,d) * 0.125*log2e (exp2 fold — softmax uses exp2f);
// k -> (b,h,n,d); v -> (b,h,d,n) with the sigma j-permutation.
// ---------------------------------------------------------------------------
__global__ __launch_bounds__(512) void qkv_gemm(
    const unsigned short* __restrict__ W,    // (1536, 512) bf16
    const unsigned short* __restrict__ xnt,  // (B, N, C) bf16
    unsigned short* __restrict__ qt,
    unsigned short* __restrict__ kt,
    unsigned short* __restrict__ vt) {
  __shared__ __align__(16) short As[256 * 64];   // 32 KB
  __shared__ __align__(16) short Bs[128 * 64];   // 16 KB

  const int n0 = blockIdx.x * 128, m0 = blockIdx.y * 256, b = blockIdx.z;
  const int t = threadIdx.x;                 // 0..511
  const int lane = t & 63, wave = t >> 6;    // 8 waves
  const int col = lane & 15, quad = lane >> 4;
  const int wRow = (wave >> 1) * 64, wCol = (wave & 1) * 64;  // 4x2 wave grid
  const unsigned short* xb = xnt + (size_t)b * N_ * C_;
  const int ldr = t >> 3;                        // 0..63: row within 64-row chunk
  const int ldc8 = (((t & 7) ^ (ldr & 7)) * 8);  // swizzled 8-short chunk
  const int cs = col & 7;

  f32x4 acc[4][4] = {};

  for (int k0 = 0; k0 < C_; k0 += 64) {
    __syncthreads();
#pragma unroll
    for (int call = 0; call < 4; ++call)
      async_copy16(&W[(size_t)(m0 + call * 64 + ldr) * C_ + k0 + ldc8],
                   &As[call * 4096 + t * 8]);
#pragma unroll
    for (int call = 0; call < 2; ++call)
      async_copy16(&xb[(size_t)(n0 + call * 64 + ldr) * C_ + k0 + ldc8],
                   &Bs[call * 4096 + t * 8]);
    asm volatile("s_waitcnt vmcnt(0)" ::: "memory");
    __syncthreads();
#pragma unroll
    for (int ks = 0; ks < 2; ++ks) {
      const int kc = ((ks * 4 + quad) ^ cs) * 8;
      bf16x8 a[4], bb[4];
#pragma unroll
      for (int i = 0; i < 4; ++i)
        a[i] = *(const bf16x8*)&As[(wRow + i * 16 + col) * 64 + kc];
#pragma unroll
      for (int j = 0; j < 4; ++j)
        bb[j] = *(const bf16x8*)&Bs[(wCol + j * 16 + col) * 64 + kc];
#pragma unroll
      for (int i = 0; i < 4; ++i)
#pragma unroll
        for (int j = 0; j < 4; ++j)
          acc[i][j] = __builtin_amdgcn_mfma_f32_16x16x32_bf16(a[i], bb[j], acc[i][j], 0, 0, 0);
    }
  }

  const int sect = m0 >> 9;                  // 256-tile lies in one 512-section
  const int mloc = (m0 & 511) + wRow;        // multiple of 64
  const int h = mloc >> 6;
  if (sect < 2) {
    unsigned short* dst = (sect == 0 ? qt : kt) + ((size_t)b * H_ + h) * N_ * D_;
    // q pre-scale folds softmax base change: exp(s/8) = 2^(s*0.125*log2e).
    // Retried via compiler-visible exp2f (R3/R6 failed with RAW-ASM exp —
    // R8 proved asm alone breaks TRANS hazard handling, R9 proved the
    // intrinsic path is safe).
    const float scl = (sect == 0) ? 0.18033688011112042f : 1.0f;
#pragma unroll
    for (int i = 0; i < 4; ++i) {
      int d0 = i * 16 + quad * 4;
#pragma unroll
      for (int j = 0; j < 4; ++j) {
        int n = n0 + wCol + j * 16 + col;
        short4v pk;
#pragma unroll
        for (int r = 0; r < 4; ++r) pk[r] = (short)f2bf(acc[i][j][r] * scl);
        *(short4v*)&dst[(size_t)n * D_ + d0] = pk;
      }
    }
  } else {
    unsigned short* dst = vt + ((size_t)b * H_ + h) * D_ * N_;
    // within-64-block j-permutation: off=j*16+col ->
    //   p = 32*(j>>1) + 8*(col>>2) + 4*(j&1) + (col&3)   (bijective)
    const int pcol = 8 * (col >> 2) + (col & 3);
#pragma unroll
    for (int i = 0; i < 4; ++i) {
      int d0 = i * 16 + quad * 4;
#pragma unroll
      for (int j = 0; j < 4; ++j) {
        int n = n0 + wCol + 32 * (j >> 1) + 4 * (j & 1) + pcol;
#pragma unroll
        for (int r = 0; r < 4; ++r)
          dst[(size_t)(d0 + r) * N_ + n] = f2bf(acc[i][j][r]);
      }
    }
  }
}

// ---------------------------------------------------------------------------
// Kernel 3: flash attention — R13 form (8 waves x 32 q-rows, grid x=bh for
// XCD K/V locality, FETCH 27 MB). One change: __expf -> exp2f (log2e folded
// into q pre-scale) — deletes 32 v_mul per wave-iter from the dominant VALU
// pipe (47.9% busy). Compiler-visible intrinsic = TRANS-hazard-safe (R9).
// ---------------------------------------------------------------------------
__global__ __launch_bounds__(512, 4) void attn(
    const unsigned short* __restrict__ qt,   // (B,H,N,D), pre-scaled x log2e/8
    const unsigned short* __restrict__ kt,   // (B,H,N,D)
    const unsigned short* __restrict__ vt,   // (B,H,D,N) j-permuted
    unsigned short* __restrict__ aot) {      // (B,N,HID)
  __shared__ __align__(16) short Kb[2][64 * 64];      // (j,d) swizzled, dbuf
  __shared__ __align__(16) short Vb[2][64 * 64];      // (d,j-perm) swizzled, dbuf

  const int bh = blockIdx.x;                 // XCD locality: bid%8 = bh%8
  const int q0 = blockIdx.y * 256;
  const int t = threadIdx.x, lane = t & 63, wave = t >> 6;
  const int col = lane & 15, quad = lane >> 4;
  const int cs = col & 7;
  const unsigned short* qp = qt + (size_t)bh * N_ * D_;
  const unsigned short* kp = kt + (size_t)bh * N_ * D_;
  const unsigned short* vp = vt + (size_t)bh * D_ * N_;
  const int r8 = t >> 3;                     // 0..63: row within a 64-row tile
  const int c8 = (((t & 7) ^ (r8 & 7)) * 8); // swizzled 8-short column chunk

  // stage Q (256x64, swizzled) across all four buffers; fragments -> regs
  async_copy16(&qp[(size_t)(q0 +   0 + r8) * D_ + c8], &Kb[0][t * 8]);
  async_copy16(&qp[(size_t)(q0 +  64 + r8) * D_ + c8], &Kb[1][t * 8]);
  async_copy16(&qp[(size_t)(q0 + 128 + r8) * D_ + c8], &Vb[0][t * 8]);
  async_copy16(&qp[(size_t)(q0 + 192 + r8) * D_ + c8], &Vb[1][t * 8]);
  asm volatile("s_waitcnt vmcnt(0)" ::: "memory");
  __syncthreads();
  const short* Qsrc = (wave < 2) ? Kb[0] : (wave < 4) ? Kb[1]
                    : (wave < 6) ? Vb[0] : Vb[1];
  const int qr0 = (wave & 1) * 32;  // global q-row of wave = wave*32
  bf16x8 qf[2][2];
#pragma unroll
  for (int i = 0; i < 2; ++i)
#pragma unroll
    for (int ks = 0; ks < 2; ++ks)
      qf[i][ks] = *(const bf16x8*)&Qsrc[(qr0 + i * 16 + col) * 64 + ((ks * 4 + quad) ^ cs) * 8];
  __syncthreads();  // all Q fragment reads done before K/V overwrite

  // K(0) -> Kb[0], V(0) -> Vb[0]
  async_copy16(&kp[(size_t)r8 * D_ + c8], &Kb[0][t * 8]);
  async_copy16(&vp[(size_t)r8 * N_ + c8], &Vb[0][t * 8]);
  asm volatile("s_waitcnt vmcnt(0)" ::: "memory");
  __syncthreads();

  bf16x8 onesb;
#pragma unroll
  for (int j = 0; j < 8; ++j) onesb[j] = (short)0x3F80;  // bf16 1.0

  f32x4 O[2][4] = {};
  f32x4 L[2] = {};

  int p = 0;
  for (int j0 = 0; j0 < N_; j0 += 64) {
    // prefetch next K/V tile into the alternate buffers; waited at iter tail
    if (j0 + 64 < N_) {
      async_copy16(&kp[(size_t)(j0 + 64 + r8) * D_ + c8], &Kb[p ^ 1][t * 8]);
      async_copy16(&vp[(size_t)r8 * N_ + (j0 + 64) + c8], &Vb[p ^ 1][t * 8]);
    }
    const short* Kc = Kb[p];
    const short* Vc = Vb[p];

    // S^T = mfma(K, Q): lane holds S[j = jtl*16 + quad*4 + r][q = i*16 + col]
    f32x4 St[2][4] = {};
#pragma unroll
    for (int jtl = 0; jtl < 4; ++jtl) {
#pragma unroll
      for (int ksd = 0; ksd < 2; ++ksd) {
        bf16x8 kb = *(const bf16x8*)&Kc[(jtl * 16 + col) * 64 + ((ksd * 4 + quad) ^ cs) * 8];
#pragma unroll
        for (int i = 0; i < 2; ++i)
          St[i][jtl] = __builtin_amdgcn_mfma_f32_16x16x32_bf16(kb, qf[i][ksd], St[i][jtl], 0, 0, 0);
      }
    }

    // PV: A-fragment = lane's own 2^S values (sigma k-order), packed via
    // __float22bfloat162_rn (compiler-visible); B = one b128 from permuted V.
#pragma unroll
    for (int ks = 0; ks < 2; ++ks) {
      bf16x8 pa[2];
#pragma unroll
      for (int i = 0; i < 2; ++i) {
        union { bf16x8 v; unsigned u[4]; } pk;
#pragma unroll
        for (int w = 0; w < 4; ++w) {
          // dword w holds elements e=2w (lo) and e=2w+1 (hi):
          //   e>>2 == w>>1, e&3 == 2*(w&1) + (e&1)
          float lo = exp2f(St[i][2 * ks + (w >> 1)][2 * (w & 1) + 0]);
          float hi = exp2f(St[i][2 * ks + (w >> 1)][2 * (w & 1) + 1]);
          __hip_bfloat162 h2 = __float22bfloat162_rn(make_float2(lo, hi));
          __builtin_memcpy(&pk.u[w], &h2, 4);
        }
        pa[i] = pk.v;
      }
#pragma unroll
      for (int dt = 0; dt < 4; ++dt) {
        bf16x8 vb = *(const bf16x8*)&Vc[(dt * 16 + col) * 64 + ((ks * 4 + quad) ^ cs) * 8];
#pragma unroll
        for (int i = 0; i < 2; ++i)
          O[i][dt] = __builtin_amdgcn_mfma_f32_16x16x32_bf16(pa[i], vb, O[i][dt], 0, 0, 0);
      }
#pragma unroll
      for (int i = 0; i < 2; ++i)
        L[i] = __builtin_amdgcn_mfma_f32_16x16x32_bf16(pa[i], onesb, L[i], 0, 0, 0);
    }

    asm volatile("s_waitcnt vmcnt(0)" ::: "memory");  // prefetch landed
    __syncthreads();         // all reads of buffers p done block-wide
    p ^= 1;
  }

  // epilogue: normalize by l, write ao_t[b][n][h*64+d]
  const int b = bh >> 3, h = bh & 7;
  unsigned short* ob = aot + (size_t)b * N_ * HID_;
#pragma unroll
  for (int i = 0; i < 2; ++i) {
#pragma unroll
    for (int r = 0; r < 4; ++r) {
      int n = q0 + wave * 32 + i * 16 + quad * 4 + r;
      float inv = 1.0f / L[i][r];
#pragma unroll
      for (int dt = 0; dt < 4; ++dt)
        ob[(size_t)n * HID_ + h * 64 + dt * 16 + col] = f2bf(O[i][dt][r] * inv);
    }
  }
}

// ---------------------------------------------------------------------------
// Kernel 4: out GEMM, BK=32 double-buffered 2-phase prefetch (unchanged).
// ---------------------------------------------------------------------------
__global__ __launch_bounds__(256) void out_gemm(
    const unsigned short* __restrict__ W,    // (512, 512) bf16
    const unsigned short* __restrict__ aot,  // (B, N, HID) bf16
    const float* __restrict__ bias,          // (512,) f32
    float* __restrict__ out) {               // (B, C, N) f32
  __shared__ __align__(16) short As[2][128 * 32];
  __shared__ __align__(16) short Bs[2][128 * 32];

  const int n0 = blockIdx.x * 128, m0 = blockIdx.y * 128, b = blockIdx.z;
  const int t = threadIdx.x;
  const int lane = t & 63, wave = t >> 6;
  const int col = lane & 15, quad = lane >> 4;
  const int wRow = (wave >> 1) * 64, wCol = (wave & 1) * 64;
  const unsigned short* xb = aot + (size_t)b * N_ * HID_;
  const int ldr = t >> 2;
  const int ldc8 = (((t & 3) ^ (ldr & 3)) * 8);
  const int kc = (quad ^ (col & 3)) * 8;

  f32x4 acc[4][4] = {};

#pragma unroll
  for (int call = 0; call < 2; ++call) {
    async_copy16(&W[(size_t)(m0 + call * 64 + ldr) * HID_ + ldc8],
                 &As[0][call * 2048 + t * 8]);
    async_copy16(&xb[(size_t)(n0 + call * 64 + ldr) * HID_ + ldc8],
                 &Bs[0][call * 2048 + t * 8]);
  }
  asm volatile("s_waitcnt vmcnt(0)" ::: "memory");
  __syncthreads();

  int p = 0;
  for (int k0 = 0; k0 < HID_; k0 += 32) {
    if (k0 + 32 < HID_) {
#pragma unroll
      for (int call = 0; call < 2; ++call) {
        async_copy16(&W[(size_t)(m0 + call * 64 + ldr) * HID_ + k0 + 32 + ldc8],
                     &As[p ^ 1][call * 2048 + t * 8]);
        async_copy16(&xb[(size_t)(n0 + call * 64 + ldr) * HID_ + k0 + 32 + ldc8],
                     &Bs[p ^ 1][call * 2048 + t * 8]);
      }
    }
    bf16x8 a[4], bb[4];
#pragma unroll
    for (int i = 0; i < 4; ++i)
      a[i] = *(const bf16x8*)&As[p][(wRow + i * 16 + col) * 32 + kc];
#pragma unroll
    for (int j = 0; j < 4; ++j)
      bb[j] = *(const bf16x8*)&Bs[p][(wCol + j * 16 + col) * 32 + kc];
#pragma unroll
    for (int i = 0; i < 4; ++i)
#pragma unroll
      for (int j = 0; j < 4; ++j)
        acc[i][j] = __builtin_amdgcn_mfma_f32_16x16x32_bf16(a[i], bb[j], acc[i][j], 0, 0, 0);
    asm volatile("s_waitcnt vmcnt(0)" ::: "memory");
    __syncthreads();
    p ^= 1;
  }

#pragma unroll
  for (int i = 0; i < 4; ++i) {
#pragma unroll
    for (int r = 0; r < 4; ++r) {
      int m = m0 + wRow + i * 16 + quad * 4 + r;
      float bv = bias[m];
#pragma unroll
      for (int j = 0; j < 4; ++j) {
        int n = n0 + wCol + j * 16 + col;
        out[((size_t)b * C_ + m) * N_ + n] = acc[i][j][r] + bv;
      }
    }
  }
}

extern "C" void kernel_launch(void* const* d_in, const int* in_sizes, int n_in,
                              void* d_out, int out_size, void* d_ws, size_t ws_size,
                              hipStream_t stream) {
  const float* x    = (const float*)d_in[0];
  const float* g    = (const float*)d_in[1];
  const float* Wqkv = (const float*)d_in[2];
  const float* Wout = (const float*)d_in[3];
  const float* bout = (const float*)d_in[4];
  float* out = (float*)d_out;

  unsigned short* ws  = (unsigned short*)d_ws;
  unsigned short* xnt = ws;                                  // B*N*C
  unsigned short* qt  = xnt + (size_t)B_ * N_ * C_;
  unsigned short* kt  = qt  + (size_t)B_ * H_ * N_ * D_;
  unsigned short* vt  = kt  + (size_t)B_ * H_ * N_ * D_;
  unsigned short* aot = vt  + (size_t)B_ * H_ * D_ * N_;     // B*N*HID
  unsigned short* Wqb = aot + (size_t)B_ * N_ * HID_;        // 1536*512
  unsigned short* Wob = Wqb + (size_t)3 * HID_ * C_;         // 512*512

  ln_transpose<<<dim3(N_ / 32, B_), 256, 0, stream>>>(
      x, g, xnt, Wqkv, Wqb, 3 * HID_ * C_ / 4, Wout, Wob, C_ * HID_ / 4);
  qkv_gemm<<<dim3(N_ / 128, 6, B_), 512, 0, stream>>>(Wqb, xnt, qt, kt, vt);
  attn<<<dim3(B_ * H_, N_ / 256), 512, 0, stream>>>(qt, kt, vt, aot);
  out_gemm<<<dim3(N_ / 128, 4, B_), 256, 0, stream>>>(Wob, aot, bout, out);
}

// Round 16
// 226.217 us; speedup vs baseline: 1.0865x; 1.0865x over previous
//
#include <hip/hip_runtime.h>
#include <hip/hip_bf16.h>
#include <stdint.h>

#define B_ 8
#define C_ 512
#define N_ 2048
#define H_ 8
#define D_ 64
#define HID_ 512

typedef short bf16x8 __attribute__((ext_vector_type(8)));
typedef float f32x4 __attribute__((ext_vector_type(4)));
typedef short short4v __attribute__((ext_vector_type(4)));

__device__ __forceinline__ float bf2f(unsigned short v) {
  union { float f; unsigned u; } c; c.u = ((unsigned)v) << 16; return c.f;
}
__device__ __forceinline__ unsigned short f2bf(float f) {
  union { float f; unsigned u; } c; c.f = f;
  unsigned u = c.u + 0x7FFFu + ((c.u >> 16) & 1u);
  return (unsigned short)(u >> 16);
}

// SESSION RULES:
//  - (R3/R6/R8, all ~0.1 absmax): no raw inline asm adjacent to TRANS-op
//    (v_exp) dataflow — INLINEASM defeats TRANS wait-state insertion.
//    R15 proved the exp2-FOLD itself is numerically fine (passed via exp2f).
//  - (R15 perf): libm exp2f() is NOT a fast intrinsic — full-precision OCML
//    path, VALU 48->64, attn +28 us. __expf (v_mul+v_exp) is the fast path.
//    exp2-fold lead CLOSED: upside <= 2 us, no verified bare-exp2 intrinsic.
//  - (R14 compile fail): __exp2f collides with glibc math.h macros.
//  - (R11 compile fail): no arrays of LDS pointers; use explicit ternaries.
//  - (R12): attn 8w x 32r and 4w x 64r both ~82-84 us — LDS-read BW is NOT
//    the attn limit; issue-mix bound at ~88% combined issue.
//  - (R13): attn grid-swap (bid%8=bh%8) cut FETCH 139->27 MB (K/V L2-resident).
//  - (R15): ln_transpose 64KB slab -> 2 blocks/CU; non-attn 147.6 -> ~137 us.

// async global->LDS, 16B per lane. LDS dest is wave-uniform base + lane*16;
// any swizzle must be applied on the GLOBAL source address.
__device__ __forceinline__ void async_copy16(const void* g, void* l) {
  __builtin_amdgcn_global_load_lds((const __attribute__((address_space(1))) void*)g,
                                   (__attribute__((address_space(3))) void*)l,
                                   16, 0, 0);
}

// ---------------------------------------------------------------------------
// Kernel 1: channel LayerNorm + transpose, SINGLE global read of x.
// 64 KB slab -> 2 blocks/CU; DMA drains and barriers overlap across blocks.
// Weight f32->bf16 conversion hidden under the slab DMA.
// ---------------------------------------------------------------------------
__global__ __launch_bounds__(256) void ln_transpose(
    const float* __restrict__ x,            // (B, C, N) f32
    const float* __restrict__ g,            // (C,) f32
    unsigned short* __restrict__ xnt,       // (B, N, C) bf16
    const float* __restrict__ Ws1, unsigned short* __restrict__ Wd1, int n1,
    const float* __restrict__ Ws2, unsigned short* __restrict__ Wd2, int n2) {
  __shared__ __align__(16) float slab[C_ * 32];            // [c][n], 64 KB
  __shared__ __align__(16) unsigned short tile2[64 * 33];  // [c-chunk][n] bf16
  __shared__ float red[256], red2[256];
  __shared__ float meanS[32], rstdS[32];

  const int b = blockIdx.y, n0 = blockIdx.x * 32;
  const int t = threadIdx.x;
  const float* xb = x + (size_t)b * C_ * N_ + n0;

  // phase 1: DMA the slab (8 lanes per c-row, 4 f32/lane, 32 rows/call)
#pragma unroll
  for (int call = 0; call < 16; ++call) {
    int c = call * 32 + (t >> 3);
    async_copy16(&xb[(size_t)c * N_ + (t & 7) * 4], &slab[call * 1024 + t * 4]);
  }

  // weight conversion (former wcvt2), overlapped with the slab DMA
  {
    const int bid = blockIdx.y * gridDim.x + blockIdx.x;  // 0..511
    for (int i = bid * 256 + t; i < n1 + n2; i += 512 * 256) {
      const float4 v = (i < n1) ? ((const float4*)Ws1)[i] : ((const float4*)Ws2)[i - n1];
      short4v pk;
      pk[0] = (short)f2bf(v.x); pk[1] = (short)f2bf(v.y);
      pk[2] = (short)f2bf(v.z); pk[3] = (short)f2bf(v.w);
      if (i < n1) ((short4v*)Wd1)[i] = pk; else ((short4v*)Wd2)[i - n1] = pk;
    }
  }

  asm volatile("s_waitcnt vmcnt(0)" ::: "memory");
  __syncthreads();

  // phase 2: stats — 8 c-partials per n (lanes vary n: 2-way, free)
  {
    const int n = t & 31, cb = (t >> 5) * 64;
    float s = 0.f, s2 = 0.f;
    for (int c = cb; c < cb + 64; ++c) {
      float v = slab[c * 32 + n];
      s += v; s2 += v * v;
    }
    red[t] = s; red2[t] = s2;
  }
  __syncthreads();
  if (t < 32) {
    float ts = 0.f, ts2 = 0.f;
#pragma unroll
    for (int k = 0; k < 8; ++k) { ts += red[t + 32 * k]; ts2 += red2[t + 32 * k]; }
    float mean = ts * (1.0f / C_);
    float var  = ts2 * (1.0f / C_) - mean * mean;
    meanS[t] = mean;
    rstdS[t] = rsqrtf(var + 1e-5f);
  }
  __syncthreads();

  unsigned short* xout = xnt + ((size_t)b * N_ + n0) * C_;
  for (int c0 = 0; c0 < C_; c0 += 64) {
    // normalize into padded tile (lanes vary n: conflict-free)
    for (int e = t; e < 64 * 32; e += 256) {
      int cl = e >> 5, nl = e & 31;
      float v = slab[(c0 + cl) * 32 + nl];
      tile2[cl * 33 + nl] = f2bf((v - meanS[nl]) * rstdS[nl] * g[c0 + cl]);
    }
    __syncthreads();
    // transposed write: 4 c per lane, consecutive lanes -> consecutive c
    for (int e = t; e < 32 * 16; e += 256) {
      int nl = e >> 4, c4 = (e & 15) * 4;
      short4v pk;
#pragma unroll
      for (int j = 0; j < 4; ++j) pk[j] = (short)tile2[(c4 + j) * 33 + nl];
      *(short4v*)&xout[(size_t)nl * C_ + c0 + c4] = pk;
    }
    __syncthreads();
  }
}

// ---------------------------------------------------------------------------
// Kernel 2: QKV GEMM. 256x128 tile (8 waves, 512 thr), BK=64, single-buffered
// R9-proven staging/read pattern. Grid (16, 6, 8) = 768 blocks; LDS 48 KB.
// Epilogue: q*0.125 (pow2 = exact bf16) -> (b,h,n,d); k -> (b,h,n,d);
// v -> (b,h,d,n) with the sigma j-permutation for attn's b128 PV reads.
// ---------------------------------------------------------------------------
__global__ __launch_bounds__(512) void qkv_gemm(
    const unsigned short* __restrict__ W,    // (1536, 512) bf16
    const unsigned short* __restrict__ xnt,  // (B, N, C) bf16
    unsigned short* __restrict__ qt,
    unsigned short* __restrict__ kt,
    unsigned short* __restrict__ vt) {
  __shared__ __align__(16) short As[256 * 64];   // 32 KB
  __shared__ __align__(16) short Bs[128 * 64];   // 16 KB

  const int n0 = blockIdx.x * 128, m0 = blockIdx.y * 256, b = blockIdx.z;
  const int t = threadIdx.x;                 // 0..511
  const int lane = t & 63, wave = t >> 6;    // 8 waves
  const int col = lane & 15, quad = lane >> 4;
  const int wRow = (wave >> 1) * 64, wCol = (wave & 1) * 64;  // 4x2 wave grid
  const unsigned short* xb = xnt + (size_t)b * N_ * C_;
  const int ldr = t >> 3;                        // 0..63: row within 64-row chunk
  const int ldc8 = (((t & 7) ^ (ldr & 7)) * 8);  // swizzled 8-short chunk
  const int cs = col & 7;

  f32x4 acc[4][4] = {};

  for (int k0 = 0; k0 < C_; k0 += 64) {
    __syncthreads();
#pragma unroll
    for (int call = 0; call < 4; ++call)
      async_copy16(&W[(size_t)(m0 + call * 64 + ldr) * C_ + k0 + ldc8],
                   &As[call * 4096 + t * 8]);
#pragma unroll
    for (int call = 0; call < 2; ++call)
      async_copy16(&xb[(size_t)(n0 + call * 64 + ldr) * C_ + k0 + ldc8],
                   &Bs[call * 4096 + t * 8]);
    asm volatile("s_waitcnt vmcnt(0)" ::: "memory");
    __syncthreads();
#pragma unroll
    for (int ks = 0; ks < 2; ++ks) {
      const int kc = ((ks * 4 + quad) ^ cs) * 8;
      bf16x8 a[4], bb[4];
#pragma unroll
      for (int i = 0; i < 4; ++i)
        a[i] = *(const bf16x8*)&As[(wRow + i * 16 + col) * 64 + kc];
#pragma unroll
      for (int j = 0; j < 4; ++j)
        bb[j] = *(const bf16x8*)&Bs[(wCol + j * 16 + col) * 64 + kc];
#pragma unroll
      for (int i = 0; i < 4; ++i)
#pragma unroll
        for (int j = 0; j < 4; ++j)
          acc[i][j] = __builtin_amdgcn_mfma_f32_16x16x32_bf16(a[i], bb[j], acc[i][j], 0, 0, 0);
    }
  }

  const int sect = m0 >> 9;                  // 256-tile lies in one 512-section
  const int mloc = (m0 & 511) + wRow;        // multiple of 64
  const int h = mloc >> 6;
  if (sect < 2) {
    unsigned short* dst = (sect == 0 ? qt : kt) + ((size_t)b * H_ + h) * N_ * D_;
    const float scl = (sect == 0) ? 0.125f : 1.0f;  // pow2 = exact in bf16
#pragma unroll
    for (int i = 0; i < 4; ++i) {
      int d0 = i * 16 + quad * 4;
#pragma unroll
      for (int j = 0; j < 4; ++j) {
        int n = n0 + wCol + j * 16 + col;
        short4v pk;
#pragma unroll
        for (int r = 0; r < 4; ++r) pk[r] = (short)f2bf(acc[i][j][r] * scl);
        *(short4v*)&dst[(size_t)n * D_ + d0] = pk;
      }
    }
  } else {
    unsigned short* dst = vt + ((size_t)b * H_ + h) * D_ * N_;
    // within-64-block j-permutation: off=j*16+col ->
    //   p = 32*(j>>1) + 8*(col>>2) + 4*(j&1) + (col&3)   (bijective)
    const int pcol = 8 * (col >> 2) + (col & 3);
#pragma unroll
    for (int i = 0; i < 4; ++i) {
      int d0 = i * 16 + quad * 4;
#pragma unroll
      for (int j = 0; j < 4; ++j) {
        int n = n0 + wCol + 32 * (j >> 1) + 4 * (j & 1) + pcol;
#pragma unroll
        for (int r = 0; r < 4; ++r)
          dst[(size_t)(d0 + r) * N_ + n] = f2bf(acc[i][j][r]);
      }
    }
  }
}

// ---------------------------------------------------------------------------
// Kernel 3: flash attention — R13-proven form verbatim (79.8 us: 8 waves x
// 32 q-rows, grid x=bh for XCD K/V locality (FETCH 27 MB), swapped QK^T,
// in-register P via sigma k-order, j-permuted V -> single b128 PV reads,
// __expf softmax, cvt_pk via __float22bfloat162_rn).
// ---------------------------------------------------------------------------
__global__ __launch_bounds__(512, 4) void attn(
    const unsigned short* __restrict__ qt,   // (B,H,N,D), pre-scaled x 0.125
    const unsigned short* __restrict__ kt,   // (B,H,N,D)
    const unsigned short* __restrict__ vt,   // (B,H,D,N) j-permuted
    unsigned short* __restrict__ aot) {      // (B,N,HID)
  __shared__ __align__(16) short Kb[2][64 * 64];      // (j,d) swizzled, dbuf
  __shared__ __align__(16) short Vb[2][64 * 64];      // (d,j-perm) swizzled, dbuf

  const int bh = blockIdx.x;                 // XCD locality: bid%8 = bh%8
  const int q0 = blockIdx.y * 256;
  const int t = threadIdx.x, lane = t & 63, wave = t >> 6;
  const int col = lane & 15, quad = lane >> 4;
  const int cs = col & 7;
  const unsigned short* qp = qt + (size_t)bh * N_ * D_;
  const unsigned short* kp = kt + (size_t)bh * N_ * D_;
  const unsigned short* vp = vt + (size_t)bh * D_ * N_;
  const int r8 = t >> 3;                     // 0..63: row within a 64-row tile
  const int c8 = (((t & 7) ^ (r8 & 7)) * 8); // swizzled 8-short column chunk

  // stage Q (256x64, swizzled) across all four buffers; fragments -> regs
  async_copy16(&qp[(size_t)(q0 +   0 + r8) * D_ + c8], &Kb[0][t * 8]);
  async_copy16(&qp[(size_t)(q0 +  64 + r8) * D_ + c8], &Kb[1][t * 8]);
  async_copy16(&qp[(size_t)(q0 + 128 + r8) * D_ + c8], &Vb[0][t * 8]);
  async_copy16(&qp[(size_t)(q0 + 192 + r8) * D_ + c8], &Vb[1][t * 8]);
  asm volatile("s_waitcnt vmcnt(0)" ::: "memory");
  __syncthreads();
  const short* Qsrc = (wave < 2) ? Kb[0] : (wave < 4) ? Kb[1]
                    : (wave < 6) ? Vb[0] : Vb[1];
  const int qr0 = (wave & 1) * 32;  // global q-row of wave = wave*32
  bf16x8 qf[2][2];
#pragma unroll
  for (int i = 0; i < 2; ++i)
#pragma unroll
    for (int ks = 0; ks < 2; ++ks)
      qf[i][ks] = *(const bf16x8*)&Qsrc[(qr0 + i * 16 + col) * 64 + ((ks * 4 + quad) ^ cs) * 8];
  __syncthreads();  // all Q fragment reads done before K/V overwrite

  // K(0) -> Kb[0], V(0) -> Vb[0]
  async_copy16(&kp[(size_t)r8 * D_ + c8], &Kb[0][t * 8]);
  async_copy16(&vp[(size_t)r8 * N_ + c8], &Vb[0][t * 8]);
  asm volatile("s_waitcnt vmcnt(0)" ::: "memory");
  __syncthreads();

  bf16x8 onesb;
#pragma unroll
  for (int j = 0; j < 8; ++j) onesb[j] = (short)0x3F80;  // bf16 1.0

  f32x4 O[2][4] = {};
  f32x4 L[2] = {};

  int p = 0;
  for (int j0 = 0; j0 < N_; j0 += 64) {
    // prefetch next K/V tile into the alternate buffers; waited at iter tail
    if (j0 + 64 < N_) {
      async_copy16(&kp[(size_t)(j0 + 64 + r8) * D_ + c8], &Kb[p ^ 1][t * 8]);
      async_copy16(&vp[(size_t)r8 * N_ + (j0 + 64) + c8], &Vb[p ^ 1][t * 8]);
    }
    const short* Kc = Kb[p];
    const short* Vc = Vb[p];

    // S^T = mfma(K, Q): lane holds S[j = jtl*16 + quad*4 + r][q = i*16 + col]
    f32x4 St[2][4] = {};
#pragma unroll
    for (int jtl = 0; jtl < 4; ++jtl) {
#pragma unroll
      for (int ksd = 0; ksd < 2; ++ksd) {
        bf16x8 kb = *(const bf16x8*)&Kc[(jtl * 16 + col) * 64 + ((ksd * 4 + quad) ^ cs) * 8];
#pragma unroll
        for (int i = 0; i < 2; ++i)
          St[i][jtl] = __builtin_amdgcn_mfma_f32_16x16x32_bf16(kb, qf[i][ksd], St[i][jtl], 0, 0, 0);
      }
    }

    // PV: A-fragment = lane's own exp'd values (sigma k-order), packed via
    // __float22bfloat162_rn (compiler-visible); B = one b128 from permuted V.
#pragma unroll
    for (int ks = 0; ks < 2; ++ks) {
      bf16x8 pa[2];
#pragma unroll
      for (int i = 0; i < 2; ++i) {
        union { bf16x8 v; unsigned u[4]; } pk;
#pragma unroll
        for (int w = 0; w < 4; ++w) {
          // dword w holds elements e=2w (lo) and e=2w+1 (hi):
          //   e>>2 == w>>1, e&3 == 2*(w&1) + (e&1)
          float lo = __expf(St[i][2 * ks + (w >> 1)][2 * (w & 1) + 0]);
          float hi = __expf(St[i][2 * ks + (w >> 1)][2 * (w & 1) + 1]);
          __hip_bfloat162 h2 = __float22bfloat162_rn(make_float2(lo, hi));
          __builtin_memcpy(&pk.u[w], &h2, 4);
        }
        pa[i] = pk.v;
      }
#pragma unroll
      for (int dt = 0; dt < 4; ++dt) {
        bf16x8 vb = *(const bf16x8*)&Vc[(dt * 16 + col) * 64 + ((ks * 4 + quad) ^ cs) * 8];
#pragma unroll
        for (int i = 0; i < 2; ++i)
          O[i][dt] = __builtin_amdgcn_mfma_f32_16x16x32_bf16(pa[i], vb, O[i][dt], 0, 0, 0);
      }
#pragma unroll
      for (int i = 0; i < 2; ++i)
        L[i] = __builtin_amdgcn_mfma_f32_16x16x32_bf16(pa[i], onesb, L[i], 0, 0, 0);
    }

    asm volatile("s_waitcnt vmcnt(0)" ::: "memory");  // prefetch landed
    __syncthreads();         // all reads of buffers p done block-wide
    p ^= 1;
  }

  // epilogue: normalize by l, write ao_t[b][n][h*64+d]
  const int b = bh >> 3, h = bh & 7;
  unsigned short* ob = aot + (size_t)b * N_ * HID_;
#pragma unroll
  for (int i = 0; i < 2; ++i) {
#pragma unroll
    for (int r = 0; r < 4; ++r) {
      int n = q0 + wave * 32 + i * 16 + quad * 4 + r;
      float inv = 1.0f / L[i][r];
#pragma unroll
      for (int dt = 0; dt < 4; ++dt)
        ob[(size_t)n * HID_ + h * 64 + dt * 16 + col] = f2bf(O[i][dt][r] * inv);
    }
  }
}

// ---------------------------------------------------------------------------
// Kernel 4: out GEMM, BK=32 double-buffered 2-phase prefetch (unchanged).
// ---------------------------------------------------------------------------
__global__ __launch_bounds__(256) void out_gemm(
    const unsigned short* __restrict__ W,    // (512, 512) bf16
    const unsigned short* __restrict__ aot,  // (B, N, HID) bf16
    const float* __restrict__ bias,          // (512,) f32
    float* __restrict__ out) {               // (B, C, N) f32
  __shared__ __align__(16) short As[2][128 * 32];
  __shared__ __align__(16) short Bs[2][128 * 32];

  const int n0 = blockIdx.x * 128, m0 = blockIdx.y * 128, b = blockIdx.z;
  const int t = threadIdx.x;
  const int lane = t & 63, wave = t >> 6;
  const int col = lane & 15, quad = lane >> 4;
  const int wRow = (wave >> 1) * 64, wCol = (wave & 1) * 64;
  const unsigned short* xb = aot + (size_t)b * N_ * HID_;
  const int ldr = t >> 2;
  const int ldc8 = (((t & 3) ^ (ldr & 3)) * 8);
  const int kc = (quad ^ (col & 3)) * 8;

  f32x4 acc[4][4] = {};

#pragma unroll
  for (int call = 0; call < 2; ++call) {
    async_copy16(&W[(size_t)(m0 + call * 64 + ldr) * HID_ + ldc8],
                 &As[0][call * 2048 + t * 8]);
    async_copy16(&xb[(size_t)(n0 + call * 64 + ldr) * HID_ + ldc8],
                 &Bs[0][call * 2048 + t * 8]);
  }
  asm volatile("s_waitcnt vmcnt(0)" ::: "memory");
  __syncthreads();

  int p = 0;
  for (int k0 = 0; k0 < HID_; k0 += 32) {
    if (k0 + 32 < HID_) {
#pragma unroll
      for (int call = 0; call < 2; ++call) {
        async_copy16(&W[(size_t)(m0 + call * 64 + ldr) * HID_ + k0 + 32 + ldc8],
                     &As[p ^ 1][call * 2048 + t * 8]);
        async_copy16(&xb[(size_t)(n0 + call * 64 + ldr) * HID_ + k0 + 32 + ldc8],
                     &Bs[p ^ 1][call * 2048 + t * 8]);
      }
    }
    bf16x8 a[4], bb[4];
#pragma unroll
    for (int i = 0; i < 4; ++i)
      a[i] = *(const bf16x8*)&As[p][(wRow + i * 16 + col) * 32 + kc];
#pragma unroll
    for (int j = 0; j < 4; ++j)
      bb[j] = *(const bf16x8*)&Bs[p][(wCol + j * 16 + col) * 32 + kc];
#pragma unroll
    for (int i = 0; i < 4; ++i)
#pragma unroll
      for (int j = 0; j < 4; ++j)
        acc[i][j] = __builtin_amdgcn_mfma_f32_16x16x32_bf16(a[i], bb[j], acc[i][j], 0, 0, 0);
    asm volatile("s_waitcnt vmcnt(0)" ::: "memory");
    __syncthreads();
    p ^= 1;
  }

#pragma unroll
  for (int i = 0; i < 4; ++i) {
#pragma unroll
    for (int r = 0; r < 4; ++r) {
      int m = m0 + wRow + i * 16 + quad * 4 + r;
      float bv = bias[m];
#pragma unroll
      for (int j = 0; j < 4; ++j) {
        int n = n0 + wCol + j * 16 + col;
        out[((size_t)b * C_ + m) * N_ + n] = acc[i][j][r] + bv;
      }
    }
  }
}

extern "C" void kernel_launch(void* const* d_in, const int* in_sizes, int n_in,
                              void* d_out, int out_size, void* d_ws, size_t ws_size,
                              hipStream_t stream) {
  const float* x    = (const float*)d_in[0];
  const float* g    = (const float*)d_in[1];
  const float* Wqkv = (const float*)d_in[2];
  const float* Wout = (const float*)d_in[3];
  const float* bout = (const float*)d_in[4];
  float* out = (float*)d_out;

  unsigned short* ws  = (unsigned short*)d_ws;
  unsigned short* xnt = ws;                                  // B*N*C
  unsigned short* qt  = xnt + (size_t)B_ * N_ * C_;
  unsigned short* kt  = qt  + (size_t)B_ * H_ * N_ * D_;
  unsigned short* vt  = kt  + (size_t)B_ * H_ * N_ * D_;
  unsigned short* aot = vt  + (size_t)B_ * H_ * D_ * N_;     // B*N*HID
  unsigned short* Wqb = aot + (size_t)B_ * N_ * HID_;        // 1536*512
  unsigned short* Wob = Wqb + (size_t)3 * HID_ * C_;         // 512*512

  ln_transpose<<<dim3(N_ / 32, B_), 256, 0, stream>>>(
      x, g, xnt, Wqkv, Wqb, 3 * HID_ * C_ / 4, Wout, Wob, C_ * HID_ / 4);
  qkv_gemm<<<dim3(N_ / 128, 6, B_), 512, 0, stream>>>(Wqb, xnt, qt, kt, vt);
  attn<<<dim3(B_ * H_, N_ / 256), 512, 0, stream>>>(qt, kt, vt, aot);
  out_gemm<<<dim3(N_ / 128, 4, B_), 256, 0, stream>>>(Wob, aot, bout, out);
}

// Round 18
// 225.743 us; speedup vs baseline: 1.0887x; 1.0021x over previous
//
#include <hip/hip_runtime.h>
#include <hip/hip_bf16.h>
#include <stdint.h>

#define B_ 8
#define C_ 512
#define N_ 2048
#define H_ 8
#define D_ 64
#define HID_ 512

typedef short bf16x8 __attribute__((ext_vector_type(8)));
typedef float f32x4 __attribute__((ext_vector_type(4)));
typedef short short4v __attribute__((ext_vector_type(4)));

__device__ __forceinline__ float bf2f(unsigned short v) {
  union { float f; unsigned u; } c; c.u = ((unsigned)v) << 16; return c.f;
}
__device__ __forceinline__ unsigned short f2bf(float f) {
  union { float f; unsigned u; } c; c.f = f;
  unsigned u = c.u + 0x7FFFu + ((c.u >> 16) & 1u);
  return (unsigned short)(u >> 16);
}

// SESSION RULES:
//  - (R3/R6/R8, all ~0.1 absmax): no raw inline asm adjacent to TRANS-op
//    (v_exp) dataflow. R15 proved the exp2-FOLD is numerically fine but
//    libm exp2f is slow (OCML full-precision, +28 us) — __expf is the path.
//  - (R14): __exp2f collides with glibc macros.
//  - (R11): no arrays of LDS pointers; explicit ternaries.
//  - (R12): attn is issue-mix bound (~91% combined), not LDS-BW bound.
//  - (R13): attn grid-swap (bid%8=bh%8) cut FETCH 139->27 MB.
//  - (R16): total-minus-attn has +-10-15 us noise; per-kernel deltas <10%
//    are invisible without counters.
//  - (R17): infra flake ("container failed twice") — re-run unchanged (R1
//    precedent: same error, clean pass on resubmit).

// async global->LDS, 16B per lane. LDS dest is wave-uniform base + lane*16;
// any swizzle must be applied on the GLOBAL source address.
__device__ __forceinline__ void async_copy16(const void* g, void* l) {
  __builtin_amdgcn_global_load_lds((const __attribute__((address_space(1))) void*)g,
                                   (__attribute__((address_space(3))) void*)l,
                                   16, 0, 0);
}

// ---------------------------------------------------------------------------
// Kernel 1: channel LayerNorm + transpose, SINGLE global read of x.
// 64 KB slab -> 2 blocks/CU; weight f32->bf16 conversion hidden under DMA.
// ---------------------------------------------------------------------------
__global__ __launch_bounds__(256) void ln_transpose(
    const float* __restrict__ x,            // (B, C, N) f32
    const float* __restrict__ g,            // (C,) f32
    unsigned short* __restrict__ xnt,       // (B, N, C) bf16
    const float* __restrict__ Ws1, unsigned short* __restrict__ Wd1, int n1,
    const float* __restrict__ Ws2, unsigned short* __restrict__ Wd2, int n2) {
  __shared__ __align__(16) float slab[C_ * 32];            // [c][n], 64 KB
  __shared__ __align__(16) unsigned short tile2[64 * 33];  // [c-chunk][n] bf16
  __shared__ float red[256], red2[256];
  __shared__ float meanS[32], rstdS[32];

  const int b = blockIdx.y, n0 = blockIdx.x * 32;
  const int t = threadIdx.x;
  const float* xb = x + (size_t)b * C_ * N_ + n0;

  // phase 1: DMA the slab (8 lanes per c-row, 4 f32/lane, 32 rows/call)
#pragma unroll
  for (int call = 0; call < 16; ++call) {
    int c = call * 32 + (t >> 3);
    async_copy16(&xb[(size_t)c * N_ + (t & 7) * 4], &slab[call * 1024 + t * 4]);
  }

  // weight conversion (former wcvt2), overlapped with the slab DMA
  {
    const int bid = blockIdx.y * gridDim.x + blockIdx.x;  // 0..511
    for (int i = bid * 256 + t; i < n1 + n2; i += 512 * 256) {
      const float4 v = (i < n1) ? ((const float4*)Ws1)[i] : ((const float4*)Ws2)[i - n1];
      short4v pk;
      pk[0] = (short)f2bf(v.x); pk[1] = (short)f2bf(v.y);
      pk[2] = (short)f2bf(v.z); pk[3] = (short)f2bf(v.w);
      if (i < n1) ((short4v*)Wd1)[i] = pk; else ((short4v*)Wd2)[i - n1] = pk;
    }
  }

  asm volatile("s_waitcnt vmcnt(0)" ::: "memory");
  __syncthreads();

  // phase 2: stats — 8 c-partials per n (lanes vary n: 2-way, free)
  {
    const int n = t & 31, cb = (t >> 5) * 64;
    float s = 0.f, s2 = 0.f;
    for (int c = cb; c < cb + 64; ++c) {
      float v = slab[c * 32 + n];
      s += v; s2 += v * v;
    }
    red[t] = s; red2[t] = s2;
  }
  __syncthreads();
  if (t < 32) {
    float ts = 0.f, ts2 = 0.f;
#pragma unroll
    for (int k = 0; k < 8; ++k) { ts += red[t + 32 * k]; ts2 += red2[t + 32 * k]; }
    float mean = ts * (1.0f / C_);
    float var  = ts2 * (1.0f / C_) - mean * mean;
    meanS[t] = mean;
    rstdS[t] = rsqrtf(var + 1e-5f);
  }
  __syncthreads();

  unsigned short* xout = xnt + ((size_t)b * N_ + n0) * C_;
  for (int c0 = 0; c0 < C_; c0 += 64) {
    // normalize into padded tile (lanes vary n: conflict-free)
    for (int e = t; e < 64 * 32; e += 256) {
      int cl = e >> 5, nl = e & 31;
      float v = slab[(c0 + cl) * 32 + nl];
      tile2[cl * 33 + nl] = f2bf((v - meanS[nl]) * rstdS[nl] * g[c0 + cl]);
    }
    __syncthreads();
    // transposed write: 4 c per lane, consecutive lanes -> consecutive c
    for (int e = t; e < 32 * 16; e += 256) {
      int nl = e >> 4, c4 = (e & 15) * 4;
      short4v pk;
#pragma unroll
      for (int j = 0; j < 4; ++j) pk[j] = (short)tile2[(c4 + j) * 33 + nl];
      *(short4v*)&xout[(size_t)nl * C_ + c0 + c4] = pk;
    }
    __syncthreads();
  }
}

// ---------------------------------------------------------------------------
// Kernel 2: QKV GEMM. 256x128 tile, BK=32, DOUBLE-BUFFERED 2-phase prefetch
// (R4-proven skeleton): issue K-tile k+1 into buffers p^1 at iter top,
// compute 16 MFMA/wave from p, single vmcnt(0)+barrier at tail — hides the
// per-iter HBM drain the single-buffered form ate 16x/block at 3 blocks/CU.
// LDS 48 KB -> occupancy unchanged. Swizzle algebra = R10-proven BK=32.
// Epilogue: q*0.125 (pow2 exact) -> (b,h,n,d); k -> (b,h,n,d);
// v -> (b,h,d,n) with the sigma j-permutation for attn's b128 PV reads.
// ---------------------------------------------------------------------------
__global__ __launch_bounds__(512) void qkv_gemm(
    const unsigned short* __restrict__ W,    // (1536, 512) bf16
    const unsigned short* __restrict__ xnt,  // (B, N, C) bf16
    unsigned short* __restrict__ qt,
    unsigned short* __restrict__ kt,
    unsigned short* __restrict__ vt) {
  __shared__ __align__(16) short As[2][256 * 32];  // 16 KB each
  __shared__ __align__(16) short Bs[2][128 * 32];  // 8 KB each

  const int n0 = blockIdx.x * 128, m0 = blockIdx.y * 256, b = blockIdx.z;
  const int t = threadIdx.x;                 // 0..511
  const int lane = t & 63, wave = t >> 6;    // 8 waves
  const int col = lane & 15, quad = lane >> 4;
  const int wRow = (wave >> 1) * 64, wCol = (wave & 1) * 64;  // 4x2 wave grid
  const unsigned short* xb = xnt + (size_t)b * N_ * C_;
  const int ldr = t >> 2;                        // 0..127: row within 128-row chunk
  const int ldc8 = (((t & 3) ^ (ldr & 3)) * 8);  // swizzled 8-short chunk
  const int kc = (quad ^ (col & 3)) * 8;         // read chunk (undoes swizzle)

  f32x4 acc[4][4] = {};

  // prologue: stage K-tile 0 into buffers 0 (As: 2 calls, Bs: 1 call)
  async_copy16(&W[(size_t)(m0 +   0 + ldr) * C_ + ldc8], &As[0][t * 8]);
  async_copy16(&W[(size_t)(m0 + 128 + ldr) * C_ + ldc8], &As[0][4096 + t * 8]);
  async_copy16(&xb[(size_t)(n0 + ldr) * C_ + ldc8], &Bs[0][t * 8]);
  asm volatile("s_waitcnt vmcnt(0)" ::: "memory");
  __syncthreads();

  int p = 0;
  for (int k0 = 0; k0 < C_; k0 += 32) {
    if (k0 + 32 < C_) {
      async_copy16(&W[(size_t)(m0 +   0 + ldr) * C_ + k0 + 32 + ldc8],
                   &As[p ^ 1][t * 8]);
      async_copy16(&W[(size_t)(m0 + 128 + ldr) * C_ + k0 + 32 + ldc8],
                   &As[p ^ 1][4096 + t * 8]);
      async_copy16(&xb[(size_t)(n0 + ldr) * C_ + k0 + 32 + ldc8],
                   &Bs[p ^ 1][t * 8]);
    }
    bf16x8 a[4], bb[4];
#pragma unroll
    for (int i = 0; i < 4; ++i)
      a[i] = *(const bf16x8*)&As[p][(wRow + i * 16 + col) * 32 + kc];
#pragma unroll
    for (int j = 0; j < 4; ++j)
      bb[j] = *(const bf16x8*)&Bs[p][(wCol + j * 16 + col) * 32 + kc];
#pragma unroll
    for (int i = 0; i < 4; ++i)
#pragma unroll
      for (int j = 0; j < 4; ++j)
        acc[i][j] = __builtin_amdgcn_mfma_f32_16x16x32_bf16(a[i], bb[j], acc[i][j], 0, 0, 0);
    asm volatile("s_waitcnt vmcnt(0)" ::: "memory");  // prefetch landed
    __syncthreads();                                  // all reads of p done
    p ^= 1;
  }

  const int sect = m0 >> 9;                  // 256-tile lies in one 512-section
  const int mloc = (m0 & 511) + wRow;        // multiple of 64
  const int h = mloc >> 6;
  if (sect < 2) {
    unsigned short* dst = (sect == 0 ? qt : kt) + ((size_t)b * H_ + h) * N_ * D_;
    const float scl = (sect == 0) ? 0.125f : 1.0f;  // pow2 = exact in bf16
#pragma unroll
    for (int i = 0; i < 4; ++i) {
      int d0 = i * 16 + quad * 4;
#pragma unroll
      for (int j = 0; j < 4; ++j) {
        int n = n0 + wCol + j * 16 + col;
        short4v pk;
#pragma unroll
        for (int r = 0; r < 4; ++r) pk[r] = (short)f2bf(acc[i][j][r] * scl);
        *(short4v*)&dst[(size_t)n * D_ + d0] = pk;
      }
    }
  } else {
    unsigned short* dst = vt + ((size_t)b * H_ + h) * D_ * N_;
    // within-64-block j-permutation: off=j*16+col ->
    //   p = 32*(j>>1) + 8*(col>>2) + 4*(j&1) + (col&3)   (bijective)
    const int pcol = 8 * (col >> 2) + (col & 3);
#pragma unroll
    for (int i = 0; i < 4; ++i) {
      int d0 = i * 16 + quad * 4;
#pragma unroll
      for (int j = 0; j < 4; ++j) {
        int n = n0 + wCol + 32 * (j >> 1) + 4 * (j & 1) + pcol;
#pragma unroll
        for (int r = 0; r < 4; ++r)
          dst[(size_t)(d0 + r) * N_ + n] = f2bf(acc[i][j][r]);
      }
    }
  }
}

// ---------------------------------------------------------------------------
// Kernel 3: flash attention — R13/R16-proven form FROZEN (79.7 us: 8 waves x
// 32 q-rows, grid x=bh for XCD K/V locality (FETCH 27 MB), swapped QK^T,
// in-register P via sigma k-order, j-permuted V -> single b128 PV reads,
// __expf softmax, cvt_pk via __float22bfloat162_rn).
// ---------------------------------------------------------------------------
__global__ __launch_bounds__(512, 4) void attn(
    const unsigned short* __restrict__ qt,   // (B,H,N,D), pre-scaled x 0.125
    const unsigned short* __restrict__ kt,   // (B,H,N,D)
    const unsigned short* __restrict__ vt,   // (B,H,D,N) j-permuted
    unsigned short* __restrict__ aot) {      // (B,N,HID)
  __shared__ __align__(16) short Kb[2][64 * 64];      // (j,d) swizzled, dbuf
  __shared__ __align__(16) short Vb[2][64 * 64];      // (d,j-perm) swizzled, dbuf

  const int bh = blockIdx.x;                 // XCD locality: bid%8 = bh%8
  const int q0 = blockIdx.y * 256;
  const int t = threadIdx.x, lane = t & 63, wave = t >> 6;
  const int col = lane & 15, quad = lane >> 4;
  const int cs = col & 7;
  const unsigned short* qp = qt + (size_t)bh * N_ * D_;
  const unsigned short* kp = kt + (size_t)bh * N_ * D_;
  const unsigned short* vp = vt + (size_t)bh * D_ * N_;
  const int r8 = t >> 3;                     // 0..63: row within a 64-row tile
  const int c8 = (((t & 7) ^ (r8 & 7)) * 8); // swizzled 8-short column chunk

  // stage Q (256x64, swizzled) across all four buffers; fragments -> regs
  async_copy16(&qp[(size_t)(q0 +   0 + r8) * D_ + c8], &Kb[0][t * 8]);
  async_copy16(&qp[(size_t)(q0 +  64 + r8) * D_ + c8], &Kb[1][t * 8]);
  async_copy16(&qp[(size_t)(q0 + 128 + r8) * D_ + c8], &Vb[0][t * 8]);
  async_copy16(&qp[(size_t)(q0 + 192 + r8) * D_ + c8], &Vb[1][t * 8]);
  asm volatile("s_waitcnt vmcnt(0)" ::: "memory");
  __syncthreads();
  const short* Qsrc = (wave < 2) ? Kb[0] : (wave < 4) ? Kb[1]
                    : (wave < 6) ? Vb[0] : Vb[1];
  const int qr0 = (wave & 1) * 32;  // global q-row of wave = wave*32
  bf16x8 qf[2][2];
#pragma unroll
  for (int i = 0; i < 2; ++i)
#pragma unroll
    for (int ks = 0; ks < 2; ++ks)
      qf[i][ks] = *(const bf16x8*)&Qsrc[(qr0 + i * 16 + col) * 64 + ((ks * 4 + quad) ^ cs) * 8];
  __syncthreads();  // all Q fragment reads done before K/V overwrite

  // K(0) -> Kb[0], V(0) -> Vb[0]
  async_copy16(&kp[(size_t)r8 * D_ + c8], &Kb[0][t * 8]);
  async_copy16(&vp[(size_t)r8 * N_ + c8], &Vb[0][t * 8]);
  asm volatile("s_waitcnt vmcnt(0)" ::: "memory");
  __syncthreads();

  bf16x8 onesb;
#pragma unroll
  for (int j = 0; j < 8; ++j) onesb[j] = (short)0x3F80;  // bf16 1.0

  f32x4 O[2][4] = {};
  f32x4 L[2] = {};

  int p = 0;
  for (int j0 = 0; j0 < N_; j0 += 64) {
    // prefetch next K/V tile into the alternate buffers; waited at iter tail
    if (j0 + 64 < N_) {
      async_copy16(&kp[(size_t)(j0 + 64 + r8) * D_ + c8], &Kb[p ^ 1][t * 8]);
      async_copy16(&vp[(size_t)r8 * N_ + (j0 + 64) + c8], &Vb[p ^ 1][t * 8]);
    }
    const short* Kc = Kb[p];
    const short* Vc = Vb[p];

    // S^T = mfma(K, Q): lane holds S[j = jtl*16 + quad*4 + r][q = i*16 + col]
    f32x4 St[2][4] = {};
#pragma unroll
    for (int jtl = 0; jtl < 4; ++jtl) {
#pragma unroll
      for (int ksd = 0; ksd < 2; ++ksd) {
        bf16x8 kb = *(const bf16x8*)&Kc[(jtl * 16 + col) * 64 + ((ksd * 4 + quad) ^ cs) * 8];
#pragma unroll
        for (int i = 0; i < 2; ++i)
          St[i][jtl] = __builtin_amdgcn_mfma_f32_16x16x32_bf16(kb, qf[i][ksd], St[i][jtl], 0, 0, 0);
      }
    }

    // PV: A-fragment = lane's own exp'd values (sigma k-order), packed via
    // __float22bfloat162_rn (compiler-visible); B = one b128 from permuted V.
#pragma unroll
    for (int ks = 0; ks < 2; ++ks) {
      bf16x8 pa[2];
#pragma unroll
      for (int i = 0; i < 2; ++i) {
        union { bf16x8 v; unsigned u[4]; } pk;
#pragma unroll
        for (int w = 0; w < 4; ++w) {
          // dword w holds elements e=2w (lo) and e=2w+1 (hi):
          //   e>>2 == w>>1, e&3 == 2*(w&1) + (e&1)
          float lo = __expf(St[i][2 * ks + (w >> 1)][2 * (w & 1) + 0]);
          float hi = __expf(St[i][2 * ks + (w >> 1)][2 * (w & 1) + 1]);
          __hip_bfloat162 h2 = __float22bfloat162_rn(make_float2(lo, hi));
          __builtin_memcpy(&pk.u[w], &h2, 4);
        }
        pa[i] = pk.v;
      }
#pragma unroll
      for (int dt = 0; dt < 4; ++dt) {
        bf16x8 vb = *(const bf16x8*)&Vc[(dt * 16 + col) * 64 + ((ks * 4 + quad) ^ cs) * 8];
#pragma unroll
        for (int i = 0; i < 2; ++i)
          O[i][dt] = __builtin_amdgcn_mfma_f32_16x16x32_bf16(pa[i], vb, O[i][dt], 0, 0, 0);
      }
#pragma unroll
      for (int i = 0; i < 2; ++i)
        L[i] = __builtin_amdgcn_mfma_f32_16x16x32_bf16(pa[i], onesb, L[i], 0, 0, 0);
    }

    asm volatile("s_waitcnt vmcnt(0)" ::: "memory");  // prefetch landed
    __syncthreads();         // all reads of buffers p done block-wide
    p ^= 1;
  }

  // epilogue: normalize by l, write ao_t[b][n][h*64+d]
  const int b = bh >> 3, h = bh & 7;
  unsigned short* ob = aot + (size_t)b * N_ * HID_;
#pragma unroll
  for (int i = 0; i < 2; ++i) {
#pragma unroll
    for (int r = 0; r < 4; ++r) {
      int n = q0 + wave * 32 + i * 16 + quad * 4 + r;
      float inv = 1.0f / L[i][r];
#pragma unroll
      for (int dt = 0; dt < 4; ++dt)
        ob[(size_t)n * HID_ + h * 64 + dt * 16 + col] = f2bf(O[i][dt][r] * inv);
    }
  }
}

// ---------------------------------------------------------------------------
// Kernel 4: out GEMM, BK=32 double-buffered 2-phase prefetch (unchanged).
// ---------------------------------------------------------------------------
__global__ __launch_bounds__(256) void out_gemm(
    const unsigned short* __restrict__ W,    // (512, 512) bf16
    const unsigned short* __restrict__ aot,  // (B, N, HID) bf16
    const float* __restrict__ bias,          // (512,) f32
    float* __restrict__ out) {               // (B, C, N) f32
  __shared__ __align__(16) short As[2][128 * 32];
  __shared__ __align__(16) short Bs[2][128 * 32];

  const int n0 = blockIdx.x * 128, m0 = blockIdx.y * 128, b = blockIdx.z;
  const int t = threadIdx.x;
  const int lane = t & 63, wave = t >> 6;
  const int col = lane & 15, quad = lane >> 4;
  const int wRow = (wave >> 1) * 64, wCol = (wave & 1) * 64;
  const unsigned short* xb = aot + (size_t)b * N_ * HID_;
  const int ldr = t >> 2;
  const int ldc8 = (((t & 3) ^ (ldr & 3)) * 8);
  const int kc = (quad ^ (col & 3)) * 8;

  f32x4 acc[4][4] = {};

#pragma unroll
  for (int call = 0; call < 2; ++call) {
    async_copy16(&W[(size_t)(m0 + call * 64 + ldr) * HID_ + ldc8],
                 &As[0][call * 2048 + t * 8]);
    async_copy16(&xb[(size_t)(n0 + call * 64 + ldr) * HID_ + ldc8],
                 &Bs[0][call * 2048 + t * 8]);
  }
  asm volatile("s_waitcnt vmcnt(0)" ::: "memory");
  __syncthreads();

  int p = 0;
  for (int k0 = 0; k0 < HID_; k0 += 32) {
    if (k0 + 32 < HID_) {
#pragma unroll
      for (int call = 0; call < 2; ++call) {
        async_copy16(&W[(size_t)(m0 + call * 64 + ldr) * HID_ + k0 + 32 + ldc8],
                     &As[p ^ 1][call * 2048 + t * 8]);
        async_copy16(&xb[(size_t)(n0 + call * 64 + ldr) * HID_ + k0 + 32 + ldc8],
                     &Bs[p ^ 1][call * 2048 + t * 8]);
      }
    }
    bf16x8 a[4], bb[4];
#pragma unroll
    for (int i = 0; i < 4; ++i)
      a[i] = *(const bf16x8*)&As[p][(wRow + i * 16 + col) * 32 + kc];
#pragma unroll
    for (int j = 0; j < 4; ++j)
      bb[j] = *(const bf16x8*)&Bs[p][(wCol + j * 16 + col) * 32 + kc];
#pragma unroll
    for (int i = 0; i < 4; ++i)
#pragma unroll
      for (int j = 0; j < 4; ++j)
        acc[i][j] = __builtin_amdgcn_mfma_f32_16x16x32_bf16(a[i], bb[j], acc[i][j], 0, 0, 0);
    asm volatile("s_waitcnt vmcnt(0)" ::: "memory");
    __syncthreads();
    p ^= 1;
  }

#pragma unroll
  for (int i = 0; i < 4; ++i) {
#pragma unroll
    for (int r = 0; r < 4; ++r) {
      int m = m0 + wRow + i * 16 + quad * 4 + r;
      float bv = bias[m];
#pragma unroll
      for (int j = 0; j < 4; ++j) {
        int n = n0 + wCol + j * 16 + col;
        out[((size_t)b * C_ + m) * N_ + n] = acc[i][j][r] + bv;
      }
    }
  }
}

extern "C" void kernel_launch(void* const* d_in, const int* in_sizes, int n_in,
                              void* d_out, int out_size, void* d_ws, size_t ws_size,
                              hipStream_t stream) {
  const float* x    = (const float*)d_in[0];
  const float* g    = (const float*)d_in[1];
  const float* Wqkv = (const float*)d_in[2];
  const float* Wout = (const float*)d_in[3];
  const float* bout = (const float*)d_in[4];
  float* out = (float*)d_out;

  unsigned short* ws  = (unsigned short*)d_ws;
  unsigned short* xnt = ws;                                  // B*N*C
  unsigned short* qt  = xnt + (size_t)B_ * N_ * C_;
  unsigned short* kt  = qt  + (size_t)B_ * H_ * N_ * D_;
  unsigned short* vt  = kt  + (size_t)B_ * H_ * N_ * D_;
  unsigned short* aot = vt  + (size_t)B_ * H_ * D_ * N_;     // B*N*HID
  unsigned short* Wqb = aot + (size_t)B_ * N_ * HID_;        // 1536*512
  unsigned short* Wob = Wqb + (size_t)3 * HID_ * C_;         // 512*512

  ln_transpose<<<dim3(N_ / 32, B_), 256, 0, stream>>>(
      x, g, xnt, Wqkv, Wqb, 3 * HID_ * C_ / 4, Wout, Wob, C_ * HID_ / 4);
  qkv_gemm<<<dim3(N_ / 128, 6, B_), 512, 0, stream>>>(Wqb, xnt, qt, kt, vt);
  attn<<<dim3(B_ * H_, N_ / 256), 512, 0, stream>>>(qt, kt, vt, aot);
  out_gemm<<<dim3(N_ / 128, 4, B_), 256, 0, stream>>>(Wob, aot, bout, out);
}

// Round 19
// 222.493 us; speedup vs baseline: 1.1046x; 1.0146x over previous
//
#include <hip/hip_runtime.h>
#include <hip/hip_bf16.h>
#include <stdint.h>

#define B_ 8
#define C_ 512
#define N_ 2048
#define H_ 8
#define D_ 64
#define HID_ 512

typedef short bf16x8 __attribute__((ext_vector_type(8)));
typedef float f32x4 __attribute__((ext_vector_type(4)));
typedef short short4v __attribute__((ext_vector_type(4)));

__device__ __forceinline__ float bf2f(unsigned short v) {
  union { float f; unsigned u; } c; c.u = ((unsigned)v) << 16; return c.f;
}
__device__ __forceinline__ unsigned short f2bf(float f) {
  union { float f; unsigned u; } c; c.f = f;
  unsigned u = c.u + 0x7FFFu + ((c.u >> 16) & 1u);
  return (unsigned short)(u >> 16);
}

// SESSION RULES:
//  - (R3/R6/R8, all ~0.1 absmax): no raw inline asm adjacent to TRANS-op
//    (v_exp) dataflow. __expf is the fast+safe softmax path (R15/R16).
//  - (R14): __exp2f collides with glibc macros; libm exp2f slow (R15).
//  - (R11): no arrays of LDS pointers; explicit ternaries.
//  - (R12): attn is issue-mix bound (~91% combined), not LDS-BW bound.
//  - (R13): attn grid-swap (bid%8=bh%8) cut FETCH 139->27 MB.
//  - (R16/R18): total-minus-attn noise +-10-15 us; three qkv restructures
//    all invisible — non-attn is diffuse, stop blind restructures.
//  - (R19): T5 s_setprio A/B on attn — compiler-visible BUILTIN (not asm,
//    TRANS-rule safe); m191 mechanism (inter-block phase diversity) matches.

// async global->LDS, 16B per lane. LDS dest is wave-uniform base + lane*16;
// any swizzle must be applied on the GLOBAL source address.
__device__ __forceinline__ void async_copy16(const void* g, void* l) {
  __builtin_amdgcn_global_load_lds((const __attribute__((address_space(1))) void*)g,
                                   (__attribute__((address_space(3))) void*)l,
                                   16, 0, 0);
}

// ---------------------------------------------------------------------------
// Kernel 1: channel LayerNorm + transpose, SINGLE global read of x.
// 64 KB slab -> 2 blocks/CU; weight f32->bf16 conversion hidden under DMA.
// ---------------------------------------------------------------------------
__global__ __launch_bounds__(256) void ln_transpose(
    const float* __restrict__ x,            // (B, C, N) f32
    const float* __restrict__ g,            // (C,) f32
    unsigned short* __restrict__ xnt,       // (B, N, C) bf16
    const float* __restrict__ Ws1, unsigned short* __restrict__ Wd1, int n1,
    const float* __restrict__ Ws2, unsigned short* __restrict__ Wd2, int n2) {
  __shared__ __align__(16) float slab[C_ * 32];            // [c][n], 64 KB
  __shared__ __align__(16) unsigned short tile2[64 * 33];  // [c-chunk][n] bf16
  __shared__ float red[256], red2[256];
  __shared__ float meanS[32], rstdS[32];

  const int b = blockIdx.y, n0 = blockIdx.x * 32;
  const int t = threadIdx.x;
  const float* xb = x + (size_t)b * C_ * N_ + n0;

  // phase 1: DMA the slab (8 lanes per c-row, 4 f32/lane, 32 rows/call)
#pragma unroll
  for (int call = 0; call < 16; ++call) {
    int c = call * 32 + (t >> 3);
    async_copy16(&xb[(size_t)c * N_ + (t & 7) * 4], &slab[call * 1024 + t * 4]);
  }

  // weight conversion (former wcvt2), overlapped with the slab DMA
  {
    const int bid = blockIdx.y * gridDim.x + blockIdx.x;  // 0..511
    for (int i = bid * 256 + t; i < n1 + n2; i += 512 * 256) {
      const float4 v = (i < n1) ? ((const float4*)Ws1)[i] : ((const float4*)Ws2)[i - n1];
      short4v pk;
      pk[0] = (short)f2bf(v.x); pk[1] = (short)f2bf(v.y);
      pk[2] = (short)f2bf(v.z); pk[3] = (short)f2bf(v.w);
      if (i < n1) ((short4v*)Wd1)[i] = pk; else ((short4v*)Wd2)[i - n1] = pk;
    }
  }

  asm volatile("s_waitcnt vmcnt(0)" ::: "memory");
  __syncthreads();

  // phase 2: stats — 8 c-partials per n (lanes vary n: 2-way, free)
  {
    const int n = t & 31, cb = (t >> 5) * 64;
    float s = 0.f, s2 = 0.f;
    for (int c = cb; c < cb + 64; ++c) {
      float v = slab[c * 32 + n];
      s += v; s2 += v * v;
    }
    red[t] = s; red2[t] = s2;
  }
  __syncthreads();
  if (t < 32) {
    float ts = 0.f, ts2 = 0.f;
#pragma unroll
    for (int k = 0; k < 8; ++k) { ts += red[t + 32 * k]; ts2 += red2[t + 32 * k]; }
    float mean = ts * (1.0f / C_);
    float var  = ts2 * (1.0f / C_) - mean * mean;
    meanS[t] = mean;
    rstdS[t] = rsqrtf(var + 1e-5f);
  }
  __syncthreads();

  unsigned short* xout = xnt + ((size_t)b * N_ + n0) * C_;
  for (int c0 = 0; c0 < C_; c0 += 64) {
    // normalize into padded tile (lanes vary n: conflict-free)
    for (int e = t; e < 64 * 32; e += 256) {
      int cl = e >> 5, nl = e & 31;
      float v = slab[(c0 + cl) * 32 + nl];
      tile2[cl * 33 + nl] = f2bf((v - meanS[nl]) * rstdS[nl] * g[c0 + cl]);
    }
    __syncthreads();
    // transposed write: 4 c per lane, consecutive lanes -> consecutive c
    for (int e = t; e < 32 * 16; e += 256) {
      int nl = e >> 4, c4 = (e & 15) * 4;
      short4v pk;
#pragma unroll
      for (int j = 0; j < 4; ++j) pk[j] = (short)tile2[(c4 + j) * 33 + nl];
      *(short4v*)&xout[(size_t)nl * C_ + c0 + c4] = pk;
    }
    __syncthreads();
  }
}

// ---------------------------------------------------------------------------
// Kernel 2: QKV GEMM. 256x128 tile, BK=32, double-buffered 2-phase prefetch
// (frozen at R18 form). Epilogue: q*0.125 -> (b,h,n,d); k -> (b,h,n,d);
// v -> (b,h,d,n) with the sigma j-permutation for attn's b128 PV reads.
// ---------------------------------------------------------------------------
__global__ __launch_bounds__(512) void qkv_gemm(
    const unsigned short* __restrict__ W,    // (1536, 512) bf16
    const unsigned short* __restrict__ xnt,  // (B, N, C) bf16
    unsigned short* __restrict__ qt,
    unsigned short* __restrict__ kt,
    unsigned short* __restrict__ vt) {
  __shared__ __align__(16) short As[2][256 * 32];  // 16 KB each
  __shared__ __align__(16) short Bs[2][128 * 32];  // 8 KB each

  const int n0 = blockIdx.x * 128, m0 = blockIdx.y * 256, b = blockIdx.z;
  const int t = threadIdx.x;                 // 0..511
  const int lane = t & 63, wave = t >> 6;    // 8 waves
  const int col = lane & 15, quad = lane >> 4;
  const int wRow = (wave >> 1) * 64, wCol = (wave & 1) * 64;  // 4x2 wave grid
  const unsigned short* xb = xnt + (size_t)b * N_ * C_;
  const int ldr = t >> 2;                        // 0..127: row within 128-row chunk
  const int ldc8 = (((t & 3) ^ (ldr & 3)) * 8);  // swizzled 8-short chunk
  const int kc = (quad ^ (col & 3)) * 8;         // read chunk (undoes swizzle)

  f32x4 acc[4][4] = {};

  // prologue: stage K-tile 0 into buffers 0 (As: 2 calls, Bs: 1 call)
  async_copy16(&W[(size_t)(m0 +   0 + ldr) * C_ + ldc8], &As[0][t * 8]);
  async_copy16(&W[(size_t)(m0 + 128 + ldr) * C_ + ldc8], &As[0][4096 + t * 8]);
  async_copy16(&xb[(size_t)(n0 + ldr) * C_ + ldc8], &Bs[0][t * 8]);
  asm volatile("s_waitcnt vmcnt(0)" ::: "memory");
  __syncthreads();

  int p = 0;
  for (int k0 = 0; k0 < C_; k0 += 32) {
    if (k0 + 32 < C_) {
      async_copy16(&W[(size_t)(m0 +   0 + ldr) * C_ + k0 + 32 + ldc8],
                   &As[p ^ 1][t * 8]);
      async_copy16(&W[(size_t)(m0 + 128 + ldr) * C_ + k0 + 32 + ldc8],
                   &As[p ^ 1][4096 + t * 8]);
      async_copy16(&xb[(size_t)(n0 + ldr) * C_ + k0 + 32 + ldc8],
                   &Bs[p ^ 1][t * 8]);
    }
    bf16x8 a[4], bb[4];
#pragma unroll
    for (int i = 0; i < 4; ++i)
      a[i] = *(const bf16x8*)&As[p][(wRow + i * 16 + col) * 32 + kc];
#pragma unroll
    for (int j = 0; j < 4; ++j)
      bb[j] = *(const bf16x8*)&Bs[p][(wCol + j * 16 + col) * 32 + kc];
#pragma unroll
    for (int i = 0; i < 4; ++i)
#pragma unroll
      for (int j = 0; j < 4; ++j)
        acc[i][j] = __builtin_amdgcn_mfma_f32_16x16x32_bf16(a[i], bb[j], acc[i][j], 0, 0, 0);
    asm volatile("s_waitcnt vmcnt(0)" ::: "memory");  // prefetch landed
    __syncthreads();                                  // all reads of p done
    p ^= 1;
  }

  const int sect = m0 >> 9;                  // 256-tile lies in one 512-section
  const int mloc = (m0 & 511) + wRow;        // multiple of 64
  const int h = mloc >> 6;
  if (sect < 2) {
    unsigned short* dst = (sect == 0 ? qt : kt) + ((size_t)b * H_ + h) * N_ * D_;
    const float scl = (sect == 0) ? 0.125f : 1.0f;  // pow2 = exact in bf16
#pragma unroll
    for (int i = 0; i < 4; ++i) {
      int d0 = i * 16 + quad * 4;
#pragma unroll
      for (int j = 0; j < 4; ++j) {
        int n = n0 + wCol + j * 16 + col;
        short4v pk;
#pragma unroll
        for (int r = 0; r < 4; ++r) pk[r] = (short)f2bf(acc[i][j][r] * scl);
        *(short4v*)&dst[(size_t)n * D_ + d0] = pk;
      }
    }
  } else {
    unsigned short* dst = vt + ((size_t)b * H_ + h) * D_ * N_;
    // within-64-block j-permutation: off=j*16+col ->
    //   p = 32*(j>>1) + 8*(col>>2) + 4*(j&1) + (col&3)   (bijective)
    const int pcol = 8 * (col >> 2) + (col & 3);
#pragma unroll
    for (int i = 0; i < 4; ++i) {
      int d0 = i * 16 + quad * 4;
#pragma unroll
      for (int j = 0; j < 4; ++j) {
        int n = n0 + wCol + 32 * (j >> 1) + 4 * (j & 1) + pcol;
#pragma unroll
        for (int r = 0; r < 4; ++r)
          dst[(size_t)(d0 + r) * N_ + n] = f2bf(acc[i][j][r]);
      }
    }
  }
}

// ---------------------------------------------------------------------------
// Kernel 3: flash attention — R13/R16 structure + T5 s_setprio A/B:
// prio 1 while issuing the S-MFMA and PV-MFMA clusters, prio 0 during the
// exp/pack VALU phase — MFMA-issuing waves win CU arbitration over the
// other block's VALU-phase waves (m191 mechanism: 2 independent blocks/CU
// at drifting phases). Builtin = compiler-visible, TRANS-rule safe.
// ---------------------------------------------------------------------------
__global__ __launch_bounds__(512, 4) void attn(
    const unsigned short* __restrict__ qt,   // (B,H,N,D), pre-scaled x 0.125
    const unsigned short* __restrict__ kt,   // (B,H,N,D)
    const unsigned short* __restrict__ vt,   // (B,H,D,N) j-permuted
    unsigned short* __restrict__ aot) {      // (B,N,HID)
  __shared__ __align__(16) short Kb[2][64 * 64];      // (j,d) swizzled, dbuf
  __shared__ __align__(16) short Vb[2][64 * 64];      // (d,j-perm) swizzled, dbuf

  const int bh = blockIdx.x;                 // XCD locality: bid%8 = bh%8
  const int q0 = blockIdx.y * 256;
  const int t = threadIdx.x, lane = t & 63, wave = t >> 6;
  const int col = lane & 15, quad = lane >> 4;
  const int cs = col & 7;
  const unsigned short* qp = qt + (size_t)bh * N_ * D_;
  const unsigned short* kp = kt + (size_t)bh * N_ * D_;
  const unsigned short* vp = vt + (size_t)bh * D_ * N_;
  const int r8 = t >> 3;                     // 0..63: row within a 64-row tile
  const int c8 = (((t & 7) ^ (r8 & 7)) * 8); // swizzled 8-short column chunk

  // stage Q (256x64, swizzled) across all four buffers; fragments -> regs
  async_copy16(&qp[(size_t)(q0 +   0 + r8) * D_ + c8], &Kb[0][t * 8]);
  async_copy16(&qp[(size_t)(q0 +  64 + r8) * D_ + c8], &Kb[1][t * 8]);
  async_copy16(&qp[(size_t)(q0 + 128 + r8) * D_ + c8], &Vb[0][t * 8]);
  async_copy16(&qp[(size_t)(q0 + 192 + r8) * D_ + c8], &Vb[1][t * 8]);
  asm volatile("s_waitcnt vmcnt(0)" ::: "memory");
  __syncthreads();
  const short* Qsrc = (wave < 2) ? Kb[0] : (wave < 4) ? Kb[1]
                    : (wave < 6) ? Vb[0] : Vb[1];
  const int qr0 = (wave & 1) * 32;  // global q-row of wave = wave*32
  bf16x8 qf[2][2];
#pragma unroll
  for (int i = 0; i < 2; ++i)
#pragma unroll
    for (int ks = 0; ks < 2; ++ks)
      qf[i][ks] = *(const bf16x8*)&Qsrc[(qr0 + i * 16 + col) * 64 + ((ks * 4 + quad) ^ cs) * 8];
  __syncthreads();  // all Q fragment reads done before K/V overwrite

  // K(0) -> Kb[0], V(0) -> Vb[0]
  async_copy16(&kp[(size_t)r8 * D_ + c8], &Kb[0][t * 8]);
  async_copy16(&vp[(size_t)r8 * N_ + c8], &Vb[0][t * 8]);
  asm volatile("s_waitcnt vmcnt(0)" ::: "memory");
  __syncthreads();

  bf16x8 onesb;
#pragma unroll
  for (int j = 0; j < 8; ++j) onesb[j] = (short)0x3F80;  // bf16 1.0

  f32x4 O[2][4] = {};
  f32x4 L[2] = {};

  int p = 0;
  for (int j0 = 0; j0 < N_; j0 += 64) {
    // prefetch next K/V tile into the alternate buffers; waited at iter tail
    if (j0 + 64 < N_) {
      async_copy16(&kp[(size_t)(j0 + 64 + r8) * D_ + c8], &Kb[p ^ 1][t * 8]);
      async_copy16(&vp[(size_t)r8 * N_ + (j0 + 64) + c8], &Vb[p ^ 1][t * 8]);
    }
    const short* Kc = Kb[p];
    const short* Vc = Vb[p];

    // S^T = mfma(K, Q): lane holds S[j = jtl*16 + quad*4 + r][q = i*16 + col]
    f32x4 St[2][4] = {};
    __builtin_amdgcn_s_setprio(1);  // T5: favor MFMA-issuing wave
#pragma unroll
    for (int jtl = 0; jtl < 4; ++jtl) {
#pragma unroll
      for (int ksd = 0; ksd < 2; ++ksd) {
        bf16x8 kb = *(const bf16x8*)&Kc[(jtl * 16 + col) * 64 + ((ksd * 4 + quad) ^ cs) * 8];
#pragma unroll
        for (int i = 0; i < 2; ++i)
          St[i][jtl] = __builtin_amdgcn_mfma_f32_16x16x32_bf16(kb, qf[i][ksd], St[i][jtl], 0, 0, 0);
      }
    }
    __builtin_amdgcn_s_setprio(0);  // back to normal for exp/pack VALU

    // PV: A-fragment = lane's own exp'd values (sigma k-order), packed via
    // __float22bfloat162_rn (compiler-visible); B = one b128 from permuted V.
#pragma unroll
    for (int ks = 0; ks < 2; ++ks) {
      bf16x8 pa[2];
#pragma unroll
      for (int i = 0; i < 2; ++i) {
        union { bf16x8 v; unsigned u[4]; } pk;
#pragma unroll
        for (int w = 0; w < 4; ++w) {
          // dword w holds elements e=2w (lo) and e=2w+1 (hi):
          //   e>>2 == w>>1, e&3 == 2*(w&1) + (e&1)
          float lo = __expf(St[i][2 * ks + (w >> 1)][2 * (w & 1) + 0]);
          float hi = __expf(St[i][2 * ks + (w >> 1)][2 * (w & 1) + 1]);
          __hip_bfloat162 h2 = __float22bfloat162_rn(make_float2(lo, hi));
          __builtin_memcpy(&pk.u[w], &h2, 4);
        }
        pa[i] = pk.v;
      }
      __builtin_amdgcn_s_setprio(1);  // T5: PV-MFMA cluster
#pragma unroll
      for (int dt = 0; dt < 4; ++dt) {
        bf16x8 vb = *(const bf16x8*)&Vc[(dt * 16 + col) * 64 + ((ks * 4 + quad) ^ cs) * 8];
#pragma unroll
        for (int i = 0; i < 2; ++i)
          O[i][dt] = __builtin_amdgcn_mfma_f32_16x16x32_bf16(pa[i], vb, O[i][dt], 0, 0, 0);
      }
#pragma unroll
      for (int i = 0; i < 2; ++i)
        L[i] = __builtin_amdgcn_mfma_f32_16x16x32_bf16(pa[i], onesb, L[i], 0, 0, 0);
      __builtin_amdgcn_s_setprio(0);
    }

    asm volatile("s_waitcnt vmcnt(0)" ::: "memory");  // prefetch landed
    __syncthreads();         // all reads of buffers p done block-wide
    p ^= 1;
  }

  // epilogue: normalize by l, write ao_t[b][n][h*64+d]
  const int b = bh >> 3, h = bh & 7;
  unsigned short* ob = aot + (size_t)b * N_ * HID_;
#pragma unroll
  for (int i = 0; i < 2; ++i) {
#pragma unroll
    for (int r = 0; r < 4; ++r) {
      int n = q0 + wave * 32 + i * 16 + quad * 4 + r;
      float inv = 1.0f / L[i][r];
#pragma unroll
      for (int dt = 0; dt < 4; ++dt)
        ob[(size_t)n * HID_ + h * 64 + dt * 16 + col] = f2bf(O[i][dt][r] * inv);
    }
  }
}

// ---------------------------------------------------------------------------
// Kernel 4: out GEMM, BK=32 double-buffered 2-phase prefetch (unchanged).
// ---------------------------------------------------------------------------
__global__ __launch_bounds__(256) void out_gemm(
    const unsigned short* __restrict__ W,    // (512, 512) bf16
    const unsigned short* __restrict__ aot,  // (B, N, HID) bf16
    const float* __restrict__ bias,          // (512,) f32
    float* __restrict__ out) {               // (B, C, N) f32
  __shared__ __align__(16) short As[2][128 * 32];
  __shared__ __align__(16) short Bs[2][128 * 32];

  const int n0 = blockIdx.x * 128, m0 = blockIdx.y * 128, b = blockIdx.z;
  const int t = threadIdx.x;
  const int lane = t & 63, wave = t >> 6;
  const int col = lane & 15, quad = lane >> 4;
  const int wRow = (wave >> 1) * 64, wCol = (wave & 1) * 64;
  const unsigned short* xb = aot + (size_t)b * N_ * HID_;
  const int ldr = t >> 2;
  const int ldc8 = (((t & 3) ^ (ldr & 3)) * 8);
  const int kc = (quad ^ (col & 3)) * 8;

  f32x4 acc[4][4] = {};

#pragma unroll
  for (int call = 0; call < 2; ++call) {
    async_copy16(&W[(size_t)(m0 + call * 64 + ldr) * HID_ + ldc8],
                 &As[0][call * 2048 + t * 8]);
    async_copy16(&xb[(size_t)(n0 + call * 64 + ldr) * HID_ + ldc8],
                 &Bs[0][call * 2048 + t * 8]);
  }
  asm volatile("s_waitcnt vmcnt(0)" ::: "memory");
  __syncthreads();

  int p = 0;
  for (int k0 = 0; k0 < HID_; k0 += 32) {
    if (k0 + 32 < HID_) {
#pragma unroll
      for (int call = 0; call < 2; ++call) {
        async_copy16(&W[(size_t)(m0 + call * 64 + ldr) * HID_ + k0 + 32 + ldc8],
                     &As[p ^ 1][call * 2048 + t * 8]);
        async_copy16(&xb[(size_t)(n0 + call * 64 + ldr) * HID_ + k0 + 32 + ldc8],
                     &Bs[p ^ 1][call * 2048 + t * 8]);
      }
    }
    bf16x8 a[4], bb[4];
#pragma unroll
    for (int i = 0; i < 4; ++i)
      a[i] = *(const bf16x8*)&As[p][(wRow + i * 16 + col) * 32 + kc];
#pragma unroll
    for (int j = 0; j < 4; ++j)
      bb[j] = *(const bf16x8*)&Bs[p][(wCol + j * 16 + col) * 32 + kc];
#pragma unroll
    for (int i = 0; i < 4; ++i)
#pragma unroll
      for (int j = 0; j < 4; ++j)
        acc[i][j] = __builtin_amdgcn_mfma_f32_16x16x32_bf16(a[i], bb[j], acc[i][j], 0, 0, 0);
    asm volatile("s_waitcnt vmcnt(0)" ::: "memory");
    __syncthreads();
    p ^= 1;
  }

#pragma unroll
  for (int i = 0; i < 4; ++i) {
#pragma unroll
    for (int r = 0; r < 4; ++r) {
      int m = m0 + wRow + i * 16 + quad * 4 + r;
      float bv = bias[m];
#pragma unroll
      for (int j = 0; j < 4; ++j) {
        int n = n0 + wCol + j * 16 + col;
        out[((size_t)b * C_ + m) * N_ + n] = acc[i][j][r] + bv;
      }
    }
  }
}

extern "C" void kernel_launch(void* const* d_in, const int* in_sizes, int n_in,
                              void* d_out, int out_size, void* d_ws, size_t ws_size,
                              hipStream_t stream) {
  const float* x    = (const float*)d_in[0];
  const float* g    = (const float*)d_in[1];
  const float* Wqkv = (const float*)d_in[2];
  const float* Wout = (const float*)d_in[3];
  const float* bout = (const float*)d_in[4];
  float* out = (float*)d_out;

  unsigned short* ws  = (unsigned short*)d_ws;
  unsigned short* xnt = ws;                                  // B*N*C
  unsigned short* qt  = xnt + (size_t)B_ * N_ * C_;
  unsigned short* kt  = qt  + (size_t)B_ * H_ * N_ * D_;
  unsigned short* vt  = kt  + (size_t)B_ * H_ * N_ * D_;
  unsigned short* aot = vt  + (size_t)B_ * H_ * D_ * N_;     // B*N*HID
  unsigned short* Wqb = aot + (size_t)B_ * N_ * HID_;        // 1536*512
  unsigned short* Wob = Wqb + (size_t)3 * HID_ * C_;         // 512*512

  ln_transpose<<<dim3(N_ / 32, B_), 256, 0, stream>>>(
      x, g, xnt, Wqkv, Wqb, 3 * HID_ * C_ / 4, Wout, Wob, C_ * HID_ / 4);
  qkv_gemm<<<dim3(N_ / 128, 6, B_), 512, 0, stream>>>(Wqb, xnt, qt, kt, vt);
  attn<<<dim3(B_ * H_, N_ / 256), 512, 0, stream>>>(qt, kt, vt, aot);
  out_gemm<<<dim3(N_ / 128, 4, B_), 256, 0, stream>>>(Wob, aot, bout, out);
}